// Round 1
// baseline (145.322 us; speedup 1.0000x reference)
//
#include <hip/hip_runtime.h>
#include <math.h>

// Problem dims
#define BB 2
#define LL 2048
#define DD 768
#define HH 12
#define EE 32
#define WW 4
#define RR 57
#define NN 20
#define PP 248          // 8 * 31 pairs

// ws layout (float offsets)
#define ENT_EMB_OFF 0                                 // B*E*D = 49152
#define ENT_ATT_OFF (BB*EE*DD)                        // + B*E*H*L = 1572864
#define Q_OFF       (ENT_ATT_OFF + BB*EE*HH*LL)       // + B*P*L = 1015808
#define QSUM_OFF    (Q_OFF + BB*PP*LL)                // + 512
#define CPART_OFF   (QSUM_OFF + 512)                  // + LSPLIT*B*P*D = 3047424

#define LSPLIT 8
#define LCHUNK 16
#define PT3 8     // pairs per block, kernel 3
#define NPT3 31   // 248/8
#define PT4 4     // pairs per block, kernel 4
#define NPT4 62   // 248/4

__device__ __forceinline__ void pair_so(int p, int& s, int& o) {
    s = p / 31;
    int r = p - s * 31;
    o = (r < s) ? r : r + 1;
}

// Kernel 1: ent_att[b,e,h,:] = mean_w attention[b,h,st+w,:]; ent_emb (h==0 blocks)
__global__ __launch_bounds__(256) void k1_ent(const float* __restrict__ seq,
                                              const float* __restrict__ att,
                                              const int* __restrict__ spans,
                                              float* __restrict__ ws) {
    int h = blockIdx.x, e = blockIdx.y, b = blockIdx.z;
    int st = spans[b * EE + e];
    const float* arow = att + ((size_t)(b * HH + h) * LL + st) * LL;
    float* orow = ws + ENT_ATT_OFF + (size_t)((b * EE + e) * HH + h) * LL;
    for (int l = threadIdx.x; l < LL; l += 256) {
        float v = 0.25f * (arow[l] + arow[LL + l] + arow[2 * LL + l] + arow[3 * LL + l]);
        orow[l] = v;
    }
    if (h == 0) {
        float* ee = ws + ENT_EMB_OFF + (size_t)(b * EE + e) * DD;
        const float* srow = seq + (size_t)(b * LL + st) * DD;
        for (int d = threadIdx.x; d < DD; d += 256) {
            ee[d] = 0.25f * (srow[d] + srow[DD + d] + srow[2 * DD + d] + srow[3 * DD + d]);
        }
    }
}

// Kernel 2: q[b,p,l] = sum_h As[h,l]*Ao[h,l]; qsum[b,p] = sum_l q
__global__ __launch_bounds__(256) void k2_q(float* __restrict__ ws) {
    int p = blockIdx.x, b = blockIdx.y;
    int s, o;
    pair_so(p, s, o);
    const float* As = ws + ENT_ATT_OFF + (size_t)((b * EE + s) * HH) * LL;
    const float* Ao = ws + ENT_ATT_OFF + (size_t)((b * EE + o) * HH) * LL;
    float* qrow = ws + Q_OFF + (size_t)(b * PP + p) * LL;
    float local = 0.f;
    for (int l = threadIdx.x; l < LL; l += 256) {
        float acc = 0.f;
        #pragma unroll
        for (int h = 0; h < HH; ++h) acc += As[h * LL + l] * Ao[h * LL + l];
        qrow[l] = acc;
        local += acc;
    }
    __shared__ float red[256];
    red[threadIdx.x] = local;
    __syncthreads();
    for (int off = 128; off > 0; off >>= 1) {
        if (threadIdx.x < off) red[threadIdx.x] += red[threadIdx.x + off];
        __syncthreads();
    }
    if (threadIdx.x == 0) ws[QSUM_OFF + b * PP + p] = red[0];
}

// Kernel 3: cpart[ls,b,p,:] = sum_{l in split ls} q[b,p,l] * seq[b,l,:]
// block: (ptile, lsplit, b), 192 threads; each thread: 4 d (float4) x 8 pairs
__global__ __launch_bounds__(192) void k3_ctx(const float* __restrict__ seq,
                                              float* __restrict__ ws) {
    int pt = blockIdx.x, ls = blockIdx.y, b = blockIdx.z;
    __shared__ __align__(16) float seq_s[LCHUNK][DD];
    __shared__ float q_s[PT3][LCHUNK];
    const float* qbase = ws + Q_OFF + (size_t)(b * PP + pt * PT3) * LL;
    float4 acc[PT3];
    #pragma unroll
    for (int j = 0; j < PT3; ++j) acc[j] = make_float4(0.f, 0.f, 0.f, 0.f);
    int tid = threadIdx.x;
    const int lbase = ls * (LL / LSPLIT);
    for (int ch = 0; ch < (LL / LSPLIT) / LCHUNK; ++ch) {
        int l0 = lbase + ch * LCHUNK;
        #pragma unroll
        for (int it = 0; it < LCHUNK; ++it) {
            ((float4*)&seq_s[it][0])[tid] =
                ((const float4*)(seq + (size_t)(b * LL + l0 + it) * DD))[tid];
        }
        if (tid < PT3 * LCHUNK) {
            q_s[tid / LCHUNK][tid % LCHUNK] =
                qbase[(size_t)(tid / LCHUNK) * LL + l0 + (tid % LCHUNK)];
        }
        __syncthreads();
        #pragma unroll
        for (int l = 0; l < LCHUNK; ++l) {
            float4 sv = ((float4*)&seq_s[l][0])[tid];
            #pragma unroll
            for (int j = 0; j < PT3; ++j) {
                float qv = q_s[j][l];
                acc[j].x += qv * sv.x;
                acc[j].y += qv * sv.y;
                acc[j].z += qv * sv.z;
                acc[j].w += qv * sv.w;
            }
        }
        __syncthreads();
    }
    float* cbase = ws + CPART_OFF;
    #pragma unroll
    for (int j = 0; j < PT3; ++j) {
        ((float4*)(cbase + (size_t)((ls * BB + b) * PP + pt * PT3 + j) * DD))[tid] = acc[j];
    }
}

// Kernel 4: build emb = [e_s, e_o, c] per pair; score vs rel (57) + nota (20, max)
__global__ __launch_bounds__(256) void k4_score(const float* __restrict__ rel,
                                                const float* __restrict__ nota,
                                                const float* __restrict__ ws,
                                                float* __restrict__ out) {
    int pt = blockIdx.x, b = blockIdx.y;
    __shared__ __align__(16) float emb_s[PT4][3 * DD];
    __shared__ float nota_s[PT4][NN];
    int tid = threadIdx.x;
    for (int idx = tid; idx < PT4 * 3 * DD; idx += 256) {
        int j = idx / (3 * DD);
        int col = idx - j * (3 * DD);
        int p = pt * PT4 + j;
        int s, o;
        pair_so(p, s, o);
        float v;
        if (col < DD) {
            v = ws[ENT_EMB_OFF + (size_t)(b * EE + s) * DD + col];
        } else if (col < 2 * DD) {
            v = ws[ENT_EMB_OFF + (size_t)(b * EE + o) * DD + (col - DD)];
        } else {
            int d = col - 2 * DD;
            float sum = 0.f;
            #pragma unroll
            for (int l = 0; l < LSPLIT; ++l)
                sum += ws[CPART_OFF + (size_t)((l * BB + b) * PP + p) * DD + d];
            v = sum / ws[QSUM_OFF + b * PP + p];
        }
        emb_s[j][col] = v;
    }
    __syncthreads();
    int wv = tid >> 6, lane = tid & 63;
    for (int row = wv; row < RR + NN; row += 4) {
        const float* code = (row < RR) ? (rel + (size_t)row * 3 * DD)
                                       : (nota + (size_t)(row - RR) * 3 * DD);
        float acc[PT4] = {0.f, 0.f, 0.f, 0.f};
        for (int k4i = lane; k4i < (3 * DD) / 4; k4i += 64) {
            float4 cv = ((const float4*)code)[k4i];
            #pragma unroll
            for (int j = 0; j < PT4; ++j) {
                float4 ev = ((const float4*)&emb_s[j][0])[k4i];
                acc[j] += cv.x * ev.x + cv.y * ev.y + cv.z * ev.z + cv.w * ev.w;
            }
        }
        #pragma unroll
        for (int j = 0; j < PT4; ++j) {
            float v = acc[j];
            #pragma unroll
            for (int off = 32; off > 0; off >>= 1) v += __shfl_xor(v, off, 64);
            if (lane == 0) {
                int p = pt * PT4 + j;
                if (row < RR) out[(size_t)(b * PP + p) * (RR + 1) + 1 + row] = v;
                else nota_s[j][row - RR] = v;
            }
        }
    }
    __syncthreads();
    if (tid < PT4) {
        float m = -INFINITY;
        #pragma unroll
        for (int n = 0; n < NN; ++n) m = fmaxf(m, nota_s[tid][n]);
        out[(size_t)(b * PP + pt * PT4 + tid) * (RR + 1)] = m;
    }
}

extern "C" void kernel_launch(void* const* d_in, const int* in_sizes, int n_in,
                              void* d_out, int out_size, void* d_ws, size_t ws_size,
                              hipStream_t stream) {
    const float* seq   = (const float*)d_in[0];
    const float* att   = (const float*)d_in[1];
    const float* rel   = (const float*)d_in[2];
    const float* nota  = (const float*)d_in[3];
    const int*   spans = (const int*)d_in[4];
    float* ws  = (float*)d_ws;
    float* out = (float*)d_out;

    k1_ent<<<dim3(HH, EE, BB), 256, 0, stream>>>(seq, att, spans, ws);
    k2_q<<<dim3(PP, BB), 256, 0, stream>>>(ws);
    k3_ctx<<<dim3(NPT3, LSPLIT, BB), 192, 0, stream>>>(seq, ws);
    k4_score<<<dim3(NPT4, BB), 256, 0, stream>>>(rel, nota, ws, out);
}

// Round 2
// 120.463 us; speedup vs baseline: 1.2064x; 1.2064x over previous
//
#include <hip/hip_runtime.h>
#include <hip/hip_bf16.h>
#include <math.h>

// Problem dims
#define BB 2
#define LL 2048
#define DD 768
#define HH 12
#define EE 32
#define RR 57
#define NN 20
#define PP 248
#define MM 256          // P padded to multiple of 64 for MFMA tiles
#define KS 8            // K-split count in context GEMM
#define KC (LL / KS)    // 256

// ws layout (float offsets)
#define ENT_EMB_OFF 0                                   // B*E*D = 49152 f
#define ENT_ATT_OFF (BB * EE * DD)                      // + B*E*H*L = 1572864 f
#define A16_OFF     (ENT_ATT_OFF + BB * EE * HH * LL)   // bf16 [B][MM][L]: B*MM*L/2 f
#define A16_F       (BB * MM * LL / 2)
#define SQT_OFF     (A16_OFF + A16_F)                   // bf16 [B][D][L]: B*D*L/2 f
#define SQT_F       (BB * DD * LL / 2)
#define CPART_OFF   (SQT_OFF + SQT_F)                   // f32 [KS][B][MM][D]

#define PT4 4     // pairs per block, kernel 4
#define NPT4 62   // 248/4

typedef __attribute__((ext_vector_type(8))) short bf16x8;
typedef __attribute__((ext_vector_type(4))) float f32x4;

__device__ __forceinline__ unsigned short f2bf(float f) {
    __hip_bfloat16 h = __float2bfloat16(f);
    return __builtin_bit_cast(unsigned short, h);
}

__device__ __forceinline__ void pair_so(int p, int& s, int& o) {
    s = p / 31;
    int r = p - s * 31;
    o = (r < s) ? r : r + 1;
}

// Kernel 0: seqT_bf16[b][d][l] = bf16(seq[b][l][d])  (B^T layout for MFMA)
__global__ __launch_bounds__(256) void k0_castT(const float* __restrict__ seq,
                                                float* __restrict__ ws) {
    int l0 = blockIdx.x * 32, d0 = blockIdx.y * 32, b = blockIdx.z;
    __shared__ float tile[32][33];
    int t = threadIdx.x;
    {
        int l = t >> 3, c = t & 7;
        float4 v = *(const float4*)(seq + (size_t)(b * LL + l0 + l) * DD + d0 + c * 4);
        tile[l][c * 4 + 0] = v.x; tile[l][c * 4 + 1] = v.y;
        tile[l][c * 4 + 2] = v.z; tile[l][c * 4 + 3] = v.w;
    }
    __syncthreads();
    int d = t >> 3, j = t & 7;
    ushort4 o = make_ushort4(f2bf(tile[j * 4 + 0][d]), f2bf(tile[j * 4 + 1][d]),
                             f2bf(tile[j * 4 + 2][d]), f2bf(tile[j * 4 + 3][d]));
    unsigned short* sqt = (unsigned short*)(ws + SQT_OFF);
    *(ushort4*)(sqt + (size_t)(b * DD + d0 + d) * LL + l0 + j * 4) = o;
}

// Kernel 1: ent_att[b,e,h,:] = mean_w attention[b,h,st+w,:]; ent_emb on h==0
__global__ __launch_bounds__(256) void k1_ent(const float* __restrict__ seq,
                                              const float* __restrict__ att,
                                              const int* __restrict__ spans,
                                              float* __restrict__ ws) {
    int h = blockIdx.x, e = blockIdx.y, b = blockIdx.z;
    int st = spans[b * EE + e];
    const float* arow = att + ((size_t)(b * HH + h) * LL + st) * LL;
    float* orow = ws + ENT_ATT_OFF + (size_t)((b * EE + e) * HH + h) * LL;
    for (int l = threadIdx.x; l < LL; l += 256) {
        orow[l] = 0.25f * (arow[l] + arow[LL + l] + arow[2 * LL + l] + arow[3 * LL + l]);
    }
    if (h == 0) {
        float* ee = ws + ENT_EMB_OFF + (size_t)(b * EE + e) * DD;
        const float* srow = seq + (size_t)(b * LL + st) * DD;
        for (int d = threadIdx.x; d < DD; d += 256) {
            ee[d] = 0.25f * (srow[d] + srow[DD + d] + srow[2 * DD + d] + srow[3 * DD + d]);
        }
    }
}

// Kernel 2: a_bf16[b][p][l] = (sum_h As*Ao) / qsum   (normalized weights, bf16)
__global__ __launch_bounds__(256) void k2_q(float* __restrict__ ws) {
    int p = blockIdx.x, b = blockIdx.y;   // p in [0,256): rows >=248 are harmless pads
    int s, o;
    pair_so(p, s, o);
    const float* As = ws + ENT_ATT_OFF + (size_t)((b * EE + s) * HH) * LL;
    const float* Ao = ws + ENT_ATT_OFF + (size_t)((b * EE + o) * HH) * LL;
    __shared__ float q_s[LL];
    __shared__ float red[4];
    int t = threadIdx.x;
    float local = 0.f;
    #pragma unroll
    for (int i = 0; i < LL / 256; ++i) {
        int l = t + 256 * i;
        float acc = 0.f;
        #pragma unroll
        for (int h = 0; h < HH; ++h) acc += As[h * LL + l] * Ao[h * LL + l];
        q_s[l] = acc;
        local += acc;
    }
    #pragma unroll
    for (int off = 32; off > 0; off >>= 1) local += __shfl_xor(local, off, 64);
    if ((t & 63) == 0) red[t >> 6] = local;
    __syncthreads();
    float inv = 1.0f / (red[0] + red[1] + red[2] + red[3]);
    unsigned short* a = (unsigned short*)(ws + A16_OFF) + (size_t)(b * MM + p) * LL;
    float4 q0 = *(float4*)&q_s[t * 8];
    float4 q1 = *(float4*)&q_s[t * 8 + 4];
    ushort4 o0 = make_ushort4(f2bf(q0.x * inv), f2bf(q0.y * inv),
                              f2bf(q0.z * inv), f2bf(q0.w * inv));
    ushort4 o1 = make_ushort4(f2bf(q1.x * inv), f2bf(q1.y * inv),
                              f2bf(q1.z * inv), f2bf(q1.w * inv));
    *(ushort4*)(a + t * 8) = o0;
    *(ushort4*)(a + t * 8 + 4) = o1;
}

// Kernel 3: cpart[ks][b][m][n] = sum_{k in split} a[m][k] * seqT[n][k]  (bf16 MFMA)
// tile 64x64, 4 waves (2x2 sub-tiles of 32x32), each wave 2x2 16x16 frags
__global__ __launch_bounds__(256) void k3_gemm(float* __restrict__ ws) {
    int m0 = blockIdx.x * 64, n0 = blockIdx.y * 64;
    int ks = blockIdx.z & (KS - 1), b = blockIdx.z >> 3;
    const unsigned short* A = (const unsigned short*)(ws + A16_OFF) + (size_t)b * MM * LL;
    const unsigned short* Bm = (const unsigned short*)(ws + SQT_OFF) + (size_t)b * DD * LL;
    __shared__ __align__(16) short As[64][40];
    __shared__ __align__(16) short Bs[64][40];
    int t = threadIdx.x;
    int row = t >> 2, seg = t & 3;          // staging: 64 rows x 4 x 16B segments
    int w = t >> 6, lane = t & 63;
    int wr = w >> 1, wc = w & 1;
    int fr = lane & 15, kb = lane >> 4;
    f32x4 acc[2][2] = {};
    int k0c = ks * KC;
    for (int st = 0; st < KC / 32; ++st) {
        int kk = k0c + st * 32;
        *(uint4*)&As[row][seg * 8] = *(const uint4*)(A + (size_t)(m0 + row) * LL + kk + seg * 8);
        *(uint4*)&Bs[row][seg * 8] = *(const uint4*)(Bm + (size_t)(n0 + row) * LL + kk + seg * 8);
        __syncthreads();
        bf16x8 af[2], bfr[2];
        #pragma unroll
        for (int i = 0; i < 2; ++i) af[i] = *(bf16x8*)&As[wr * 32 + i * 16 + fr][kb * 8];
        #pragma unroll
        for (int j = 0; j < 2; ++j) bfr[j] = *(bf16x8*)&Bs[wc * 32 + j * 16 + fr][kb * 8];
        #pragma unroll
        for (int i = 0; i < 2; ++i)
            #pragma unroll
            for (int j = 0; j < 2; ++j)
                acc[i][j] = __builtin_amdgcn_mfma_f32_16x16x32_bf16(af[i], bfr[j], acc[i][j], 0, 0, 0);
        __syncthreads();
    }
    float* cp = ws + CPART_OFF + (size_t)((ks * BB + b) * MM) * DD;
    #pragma unroll
    for (int i = 0; i < 2; ++i)
        #pragma unroll
        for (int j = 0; j < 2; ++j)
            #pragma unroll
            for (int r = 0; r < 4; ++r) {
                int gm = m0 + wr * 32 + i * 16 + kb * 4 + r;
                int gn = n0 + wc * 32 + j * 16 + fr;
                cp[(size_t)gm * DD + gn] = acc[i][j][r];
            }
}

// Kernel 4: emb = [e_s, e_o, c]; scores vs rel(57) + nota(20, max)
__global__ __launch_bounds__(256) void k4_score(const float* __restrict__ rel,
                                                const float* __restrict__ nota,
                                                const float* __restrict__ ws,
                                                float* __restrict__ out) {
    int pt = blockIdx.x, b = blockIdx.y;
    __shared__ __align__(16) float emb_s[PT4][3 * DD];
    __shared__ float nota_s[PT4][NN];
    int tid = threadIdx.x;
    for (int idx = tid; idx < PT4 * 3 * DD; idx += 256) {
        int j = idx / (3 * DD);
        int col = idx - j * (3 * DD);
        int p = pt * PT4 + j;
        int s, o;
        pair_so(p, s, o);
        float v;
        if (col < DD) {
            v = ws[ENT_EMB_OFF + (size_t)(b * EE + s) * DD + col];
        } else if (col < 2 * DD) {
            v = ws[ENT_EMB_OFF + (size_t)(b * EE + o) * DD + (col - DD)];
        } else {
            int d = col - 2 * DD;
            float sum = 0.f;
            #pragma unroll
            for (int ls = 0; ls < KS; ++ls)
                sum += ws[CPART_OFF + (size_t)((ls * BB + b) * MM + p) * DD + d];
            v = sum;
        }
        emb_s[j][col] = v;
    }
    __syncthreads();
    int wv = tid >> 6, lane = tid & 63;
    for (int rowi = wv; rowi < RR + NN; rowi += 4) {
        const float* code = (rowi < RR) ? (rel + (size_t)rowi * 3 * DD)
                                        : (nota + (size_t)(rowi - RR) * 3 * DD);
        float acc[PT4] = {0.f, 0.f, 0.f, 0.f};
        for (int k4i = lane; k4i < (3 * DD) / 4; k4i += 64) {
            float4 cv = ((const float4*)code)[k4i];
            #pragma unroll
            for (int j = 0; j < PT4; ++j) {
                float4 ev = ((const float4*)&emb_s[j][0])[k4i];
                acc[j] += cv.x * ev.x + cv.y * ev.y + cv.z * ev.z + cv.w * ev.w;
            }
        }
        #pragma unroll
        for (int j = 0; j < PT4; ++j) {
            float v = acc[j];
            #pragma unroll
            for (int off = 32; off > 0; off >>= 1) v += __shfl_xor(v, off, 64);
            if (lane == 0) {
                int p = pt * PT4 + j;
                if (rowi < RR) out[(size_t)(b * PP + p) * (RR + 1) + 1 + rowi] = v;
                else nota_s[j][rowi - RR] = v;
            }
        }
    }
    __syncthreads();
    if (tid < PT4) {
        float m = -INFINITY;
        #pragma unroll
        for (int n = 0; n < NN; ++n) m = fmaxf(m, nota_s[tid][n]);
        out[(size_t)(b * PP + pt * PT4 + tid) * (RR + 1)] = m;
    }
}

extern "C" void kernel_launch(void* const* d_in, const int* in_sizes, int n_in,
                              void* d_out, int out_size, void* d_ws, size_t ws_size,
                              hipStream_t stream) {
    const float* seq   = (const float*)d_in[0];
    const float* att   = (const float*)d_in[1];
    const float* rel   = (const float*)d_in[2];
    const float* nota  = (const float*)d_in[3];
    const int*   spans = (const int*)d_in[4];
    float* ws  = (float*)d_ws;
    float* out = (float*)d_out;

    k0_castT<<<dim3(LL / 32, DD / 32, BB), 256, 0, stream>>>(seq, ws);
    k1_ent<<<dim3(HH, EE, BB), 256, 0, stream>>>(seq, att, spans, ws);
    k2_q<<<dim3(MM, BB), 256, 0, stream>>>(ws);
    k3_gemm<<<dim3(MM / 64, DD / 64, KS * BB), 256, 0, stream>>>(ws);
    k4_score<<<dim3(NPT4, BB), 256, 0, stream>>>(rel, nota, ws, out);
}

// Round 3
// 118.671 us; speedup vs baseline: 1.2246x; 1.0151x over previous
//
#include <hip/hip_runtime.h>
#include <hip/hip_bf16.h>
#include <math.h>

// Problem dims
#define BB 2
#define LL 2048
#define DD 768
#define HH 12
#define EE 32
#define RR 57
#define NN 20
#define PP 248
#define MM 256          // P padded to 256 for MFMA tiles
#define KS 8            // K-split in context GEMM
#define KCH (LL / KS)   // 256

// ws layout (float offsets)
#define ENT_EMB_OFF 0                                   // B*E*D
#define ENT_ATT_OFF (BB * EE * DD)                      // B*E*H*L f32
#define A16_OFF     (ENT_ATT_OFF + BB * EE * HH * LL)   // bf16 [B][MM][LL] (unnormalized q)
#define A16_F       (BB * MM * LL / 2)
#define SQT_OFF     (A16_OFF + A16_F)                   // bf16 [B][DD][LL]
#define SQT_F       (BB * DD * LL / 2)
#define CPART_OFF   (SQT_OFF + SQT_F)                   // f32 [KS][B][MM][DD]

#define PT4 4
#define NPT4 62

typedef __attribute__((ext_vector_type(8))) short bf16x8;
typedef __attribute__((ext_vector_type(4))) float f32x4;

__device__ __forceinline__ unsigned short f2bf(float f) {
    __hip_bfloat16 h = __float2bfloat16(f);
    return __builtin_bit_cast(unsigned short, h);
}
__device__ __forceinline__ float bf2f(unsigned short u) {
    unsigned int x = ((unsigned int)u) << 16;
    return __builtin_bit_cast(float, x);
}
__device__ __forceinline__ void pair_so(int p, int& s, int& o) {
    s = p / 31;
    int r = p - s * 31;
    o = (r < s) ? r : r + 1;
}

// Kernel A (fused): role 0 (bx<3072): seqT cast-transpose; role 1: entity gather
__global__ __launch_bounds__(256) void kA(const float* __restrict__ seq,
                                          const float* __restrict__ att,
                                          const int* __restrict__ spans,
                                          float* __restrict__ ws) {
    __shared__ float tile[32][33];
    int bx = blockIdx.x;
    int t = threadIdx.x;
    if (bx < 3072) {
        int b = bx / 1536, rem = bx % 1536;
        int l0 = (rem % 64) * 32, d0 = (rem / 64) * 32;
        {
            int l = t >> 3, c = t & 7;
            float4 v = *(const float4*)(seq + (size_t)(b * LL + l0 + l) * DD + d0 + c * 4);
            tile[l][c * 4 + 0] = v.x; tile[l][c * 4 + 1] = v.y;
            tile[l][c * 4 + 2] = v.z; tile[l][c * 4 + 3] = v.w;
        }
        __syncthreads();
        int d = t >> 3, j = t & 7;
        ushort4 o = make_ushort4(f2bf(tile[j * 4 + 0][d]), f2bf(tile[j * 4 + 1][d]),
                                 f2bf(tile[j * 4 + 2][d]), f2bf(tile[j * 4 + 3][d]));
        unsigned short* sqt = (unsigned short*)(ws + SQT_OFF);
        *(ushort4*)(sqt + (size_t)(b * DD + d0 + d) * LL + l0 + j * 4) = o;
    } else {
        int bx2 = bx - 3072;
        int h = bx2 % HH, e = (bx2 / HH) % EE, b = bx2 / (HH * EE);
        int st = spans[b * EE + e];
        const float* arow = att + ((size_t)(b * HH + h) * LL + st) * LL;
        float* orow = ws + ENT_ATT_OFF + (size_t)((b * EE + e) * HH + h) * LL;
        for (int l = t; l < LL; l += 256) {
            orow[l] = 0.25f * (arow[l] + arow[LL + l] + arow[2 * LL + l] + arow[3 * LL + l]);
        }
        if (h == 0) {
            float* ee = ws + ENT_EMB_OFF + (size_t)(b * EE + e) * DD;
            const float* srow = seq + (size_t)(b * LL + st) * DD;
            for (int d = t; d < DD; d += 256) {
                ee[d] = 0.25f * (srow[d] + srow[DD + d] + srow[2 * DD + d] + srow[3 * DD + d]);
            }
        }
    }
}

// Kernel B: per (b, l-chunk of 32): stage att chunk once, compute all 256 pairs.
// q unnormalized -> bf16 A[m][l]  (rows >= 248 are pads, never consumed downstream)
__global__ __launch_bounds__(256) void kB(float* __restrict__ ws) {
    int l0 = blockIdx.x * 32, b = blockIdx.y;
    __shared__ float att_s[32][EE * HH];   // [l][e*12+h], 48 KB
    int t = threadIdx.x;
    const float* EA = ws + ENT_ATT_OFF + (size_t)b * EE * HH * LL;
    for (int i = t; i < EE * HH * 8; i += 256) {
        int row = i >> 3, seg = i & 7;
        float4 v = *(const float4*)(EA + (size_t)row * LL + l0 + seg * 4);
        att_s[seg * 4 + 0][row] = v.x;
        att_s[seg * 4 + 1][row] = v.y;
        att_s[seg * 4 + 2][row] = v.z;
        att_s[seg * 4 + 3][row] = v.w;
    }
    __syncthreads();
    int p = t, s, o;
    pair_so(p, s, o);           // s in [0,8]; s==8 only for pad rows (valid index)
    float q[32];
    #pragma unroll
    for (int l = 0; l < 32; ++l) {
        float acc = 0.f;
        #pragma unroll
        for (int h = 0; h < HH; ++h) acc += att_s[l][s * HH + h] * att_s[l][o * HH + h];
        q[l] = acc;
    }
    unsigned short* A16 = (unsigned short*)(ws + A16_OFF) + (size_t)(b * MM + p) * LL + l0;
    #pragma unroll
    for (int i = 0; i < 8; ++i) {
        ushort4 ov = make_ushort4(f2bf(q[i * 4 + 0]), f2bf(q[i * 4 + 1]),
                                  f2bf(q[i * 4 + 2]), f2bf(q[i * 4 + 3]));
        *(ushort4*)(A16 + i * 4) = ov;
    }
}

// Kernel C: cpart[ks][b][m][n] = sum_{k in split} A[m][k] * seqT[n][k]  (bf16 MFMA)
__global__ __launch_bounds__(256) void kC(float* __restrict__ ws) {
    int m0 = blockIdx.x * 64, n0 = blockIdx.y * 64;
    int ks = blockIdx.z & (KS - 1), b = blockIdx.z >> 3;
    const unsigned short* A = (const unsigned short*)(ws + A16_OFF) + (size_t)b * MM * LL;
    const unsigned short* Bm = (const unsigned short*)(ws + SQT_OFF) + (size_t)b * DD * LL;
    __shared__ __align__(16) short As[64][40];
    __shared__ __align__(16) short Bs[64][40];
    int t = threadIdx.x;
    int row = t >> 2, seg = t & 3;
    int w = t >> 6, lane = t & 63;
    int wr = w >> 1, wc = w & 1;
    int fr = lane & 15, kb = lane >> 4;
    f32x4 acc[2][2] = {};
    int k0c = ks * KCH;
    for (int st = 0; st < KCH / 32; ++st) {
        int kk = k0c + st * 32;
        *(uint4*)&As[row][seg * 8] = *(const uint4*)(A + (size_t)(m0 + row) * LL + kk + seg * 8);
        *(uint4*)&Bs[row][seg * 8] = *(const uint4*)(Bm + (size_t)(n0 + row) * LL + kk + seg * 8);
        __syncthreads();
        bf16x8 af[2], bfr[2];
        #pragma unroll
        for (int i = 0; i < 2; ++i) af[i] = *(bf16x8*)&As[wr * 32 + i * 16 + fr][kb * 8];
        #pragma unroll
        for (int j = 0; j < 2; ++j) bfr[j] = *(bf16x8*)&Bs[wc * 32 + j * 16 + fr][kb * 8];
        #pragma unroll
        for (int i = 0; i < 2; ++i)
            #pragma unroll
            for (int j = 0; j < 2; ++j)
                acc[i][j] = __builtin_amdgcn_mfma_f32_16x16x32_bf16(af[i], bfr[j], acc[i][j], 0, 0, 0);
        __syncthreads();
    }
    float* cp = ws + CPART_OFF + (size_t)((ks * BB + b) * MM) * DD;
    #pragma unroll
    for (int i = 0; i < 2; ++i)
        #pragma unroll
        for (int j = 0; j < 2; ++j)
            #pragma unroll
            for (int r = 0; r < 4; ++r) {
                int gm = m0 + wr * 32 + i * 16 + kb * 4 + r;
                int gn = n0 + wc * 32 + j * 16 + fr;
                cp[(size_t)gm * DD + gn] = acc[i][j][r];
            }
}

// Kernel D: qsum (from bf16 q rows) + emb=[e_s,e_o,c/qsum] + scoring
__global__ __launch_bounds__(256) void kD(const float* __restrict__ rel,
                                          const float* __restrict__ nota,
                                          const float* __restrict__ ws,
                                          float* __restrict__ out) {
    int pt = blockIdx.x, b = blockIdx.y;
    __shared__ __align__(16) float emb_s[PT4][3 * DD];
    __shared__ float nota_s[PT4][NN];
    __shared__ float red_s[4][PT4];
    __shared__ float qs_s[PT4];
    int tid = threadIdx.x;
    // phase 0: qsum per pair
    {
        const unsigned short* A16 =
            (const unsigned short*)(ws + A16_OFF) + (size_t)(b * MM + pt * PT4) * LL;
        #pragma unroll
        for (int j = 0; j < PT4; ++j) {
            ushort4 u0 = *(const ushort4*)(A16 + (size_t)j * LL + tid * 8);
            ushort4 u1 = *(const ushort4*)(A16 + (size_t)j * LL + tid * 8 + 4);
            float v = bf2f(u0.x) + bf2f(u0.y) + bf2f(u0.z) + bf2f(u0.w)
                    + bf2f(u1.x) + bf2f(u1.y) + bf2f(u1.z) + bf2f(u1.w);
            #pragma unroll
            for (int off = 32; off > 0; off >>= 1) v += __shfl_xor(v, off, 64);
            if ((tid & 63) == 0) red_s[tid >> 6][j] = v;
        }
        __syncthreads();
        if (tid < PT4)
            qs_s[tid] = 1.0f / (red_s[0][tid] + red_s[1][tid] + red_s[2][tid] + red_s[3][tid]);
        __syncthreads();
    }
    // phase 1: emb build
    for (int idx = tid; idx < PT4 * 3 * DD; idx += 256) {
        int j = idx / (3 * DD);
        int col = idx - j * (3 * DD);
        int p = pt * PT4 + j;
        int s, o;
        pair_so(p, s, o);
        float v;
        if (col < DD) {
            v = ws[ENT_EMB_OFF + (size_t)(b * EE + s) * DD + col];
        } else if (col < 2 * DD) {
            v = ws[ENT_EMB_OFF + (size_t)(b * EE + o) * DD + (col - DD)];
        } else {
            int d = col - 2 * DD;
            float sum = 0.f;
            #pragma unroll
            for (int ls = 0; ls < KS; ++ls)
                sum += ws[CPART_OFF + (size_t)((ls * BB + b) * MM + p) * DD + d];
            v = sum * qs_s[j];
        }
        emb_s[j][col] = v;
    }
    __syncthreads();
    // phase 2: scoring
    int wv = tid >> 6, lane = tid & 63;
    for (int rowi = wv; rowi < RR + NN; rowi += 4) {
        const float* code = (rowi < RR) ? (rel + (size_t)rowi * 3 * DD)
                                        : (nota + (size_t)(rowi - RR) * 3 * DD);
        float acc[PT4] = {0.f, 0.f, 0.f, 0.f};
        for (int k4i = lane; k4i < (3 * DD) / 4; k4i += 64) {
            float4 cv = ((const float4*)code)[k4i];
            #pragma unroll
            for (int j = 0; j < PT4; ++j) {
                float4 ev = ((const float4*)&emb_s[j][0])[k4i];
                acc[j] += cv.x * ev.x + cv.y * ev.y + cv.z * ev.z + cv.w * ev.w;
            }
        }
        #pragma unroll
        for (int j = 0; j < PT4; ++j) {
            float v = acc[j];
            #pragma unroll
            for (int off = 32; off > 0; off >>= 1) v += __shfl_xor(v, off, 64);
            if (lane == 0) {
                int p = pt * PT4 + j;
                if (rowi < RR) out[(size_t)(b * PP + p) * (RR + 1) + 1 + rowi] = v;
                else nota_s[j][rowi - RR] = v;
            }
        }
    }
    __syncthreads();
    if (tid < PT4) {
        float m = -INFINITY;
        #pragma unroll
        for (int n = 0; n < NN; ++n) m = fmaxf(m, nota_s[tid][n]);
        out[(size_t)(b * PP + pt * PT4 + tid) * (RR + 1)] = m;
    }
}

extern "C" void kernel_launch(void* const* d_in, const int* in_sizes, int n_in,
                              void* d_out, int out_size, void* d_ws, size_t ws_size,
                              hipStream_t stream) {
    const float* seq   = (const float*)d_in[0];
    const float* att   = (const float*)d_in[1];
    const float* rel   = (const float*)d_in[2];
    const float* nota  = (const float*)d_in[3];
    const int*   spans = (const int*)d_in[4];
    float* ws  = (float*)d_ws;
    float* out = (float*)d_out;

    kA<<<3072 + HH * EE * BB, 256, 0, stream>>>(seq, att, spans, ws);
    kB<<<dim3(LL / 32, BB), 256, 0, stream>>>(ws);
    kC<<<dim3(MM / 64, DD / 64, KS * BB), 256, 0, stream>>>(ws);
    kD<<<dim3(NPT4, BB), 256, 0, stream>>>(rel, nota, ws, out);
}

// Round 4
// 74.322 us; speedup vs baseline: 1.9553x; 1.5967x over previous
//
#include <hip/hip_runtime.h>
#include <hip/hip_bf16.h>
#include <math.h>

// Problem dims
#define BB 2
#define LL 2048
#define DD 768
#define HH 12
#define EE 32
#define RR 57
#define NN 20
#define PP 248
#define MM 256          // P padded to 256 for MFMA tiles
#define KS 8            // K-split in context GEMM
#define KCH (LL / KS)   // 256

// ws layout (float offsets)
#define ENT_EMB_OFF 0                          // B*E*D f32
#define A16_OFF   (BB * EE * DD)               // bf16 [B][MM][LL] (unnormalized q)
#define A16_F     (BB * MM * LL / 2)
#define SQT_OFF   (A16_OFF + A16_F)            // bf16 [B][DD][LL]
#define SQT_F     (BB * DD * LL / 2)
#define CPART_OFF (SQT_OFF + SQT_F)            // f32 [KS][B][MM][DD]

#define PT4 4
#define NPT4 62

typedef __attribute__((ext_vector_type(8))) short bf16x8;
typedef __attribute__((ext_vector_type(4))) float f32x4;

__device__ __forceinline__ unsigned short f2bf(float f) {
    __hip_bfloat16 h = __float2bfloat16(f);
    return __builtin_bit_cast(unsigned short, h);
}
__device__ __forceinline__ float bf2f(unsigned short u) {
    unsigned int x = ((unsigned int)u) << 16;
    return __builtin_bit_cast(float, x);
}
__device__ __forceinline__ void pair_so(int p, int& s, int& o) {
    s = p / 31;
    int r = p - s * 31;
    o = (r < s) ? r : r + 1;
}

// Kernel 1: role 0 (bx<3072): seqT bf16 cast-transpose; role 1 (64 blocks): ent_emb
__global__ __launch_bounds__(256) void k1_prep(const float* __restrict__ seq,
                                               const int* __restrict__ spans,
                                               float* __restrict__ ws) {
    __shared__ float tile[32][33];
    int bx = blockIdx.x;
    int t = threadIdx.x;
    if (bx < 3072) {
        int b = bx / 1536, rem = bx % 1536;
        int l0 = (rem % 64) * 32, d0 = (rem / 64) * 32;
        {
            int l = t >> 3, c = t & 7;
            float4 v = *(const float4*)(seq + (size_t)(b * LL + l0 + l) * DD + d0 + c * 4);
            tile[l][c * 4 + 0] = v.x; tile[l][c * 4 + 1] = v.y;
            tile[l][c * 4 + 2] = v.z; tile[l][c * 4 + 3] = v.w;
        }
        __syncthreads();
        int d = t >> 3, j = t & 7;
        ushort4 o = make_ushort4(f2bf(tile[j * 4 + 0][d]), f2bf(tile[j * 4 + 1][d]),
                                 f2bf(tile[j * 4 + 2][d]), f2bf(tile[j * 4 + 3][d]));
        unsigned short* sqt = (unsigned short*)(ws + SQT_OFF);
        *(ushort4*)(sqt + (size_t)(b * DD + d0 + d) * LL + l0 + j * 4) = o;
    } else {
        int bx2 = bx - 3072;
        int e = bx2 & 31, b = bx2 >> 5;
        int st = spans[b * EE + e];
        float* ee = ws + ENT_EMB_OFF + (size_t)(b * EE + e) * DD;
        const float* srow = seq + (size_t)(b * LL + st) * DD;
        for (int d = t; d < DD; d += 256) {
            ee[d] = 0.25f * (srow[d] + srow[DD + d] + srow[2 * DD + d] + srow[3 * DD + d]);
        }
    }
}

// Kernel 2: per (b, 32-l-chunk): gather+w-average attention directly into LDS,
// then compute all 256 pair rows: q[p][l] = sum_h As*Ao (unnormalized, bf16 out)
__global__ __launch_bounds__(256) void k2_q(const float* __restrict__ att,
                                            const int* __restrict__ spans,
                                            float* __restrict__ ws) {
    int l0 = blockIdx.x * 32, b = blockIdx.y;
    __shared__ float att_s[32][EE * HH + 1];   // [l][e*12+h], pad->49.3 KB
    __shared__ int sp_s[EE];
    int t = threadIdx.x;
    if (t < EE) sp_s[t] = spans[b * EE + t];
    __syncthreads();
    // 384 (e,h) rows x 8 segments of 4 l; average the 4 w-rows inline
    for (int i = t; i < EE * HH * 8; i += 256) {
        int seg = i & 7, eh = i >> 3;
        int e = eh / HH, h = eh - e * HH;
        const float* base = att + ((size_t)(b * HH + h) * LL + sp_s[e]) * LL + l0 + seg * 4;
        float4 v0 = *(const float4*)base;
        float4 v1 = *(const float4*)(base + LL);
        float4 v2 = *(const float4*)(base + 2 * LL);
        float4 v3 = *(const float4*)(base + 3 * LL);
        att_s[seg * 4 + 0][eh] = 0.25f * (v0.x + v1.x + v2.x + v3.x);
        att_s[seg * 4 + 1][eh] = 0.25f * (v0.y + v1.y + v2.y + v3.y);
        att_s[seg * 4 + 2][eh] = 0.25f * (v0.z + v1.z + v2.z + v3.z);
        att_s[seg * 4 + 3][eh] = 0.25f * (v0.w + v1.w + v2.w + v3.w);
    }
    __syncthreads();
    int p = t, s, o;
    pair_so(p, s, o);          // s<=8, o<=31: always valid entity indices
    float q[32];
    #pragma unroll
    for (int l = 0; l < 32; ++l) {
        float acc = 0.f;
        #pragma unroll
        for (int h = 0; h < HH; ++h) acc += att_s[l][s * HH + h] * att_s[l][o * HH + h];
        q[l] = acc;
    }
    unsigned short* A16 = (unsigned short*)(ws + A16_OFF) + (size_t)(b * MM + p) * LL + l0;
    #pragma unroll
    for (int i = 0; i < 8; ++i) {
        ushort4 ov = make_ushort4(f2bf(q[i * 4 + 0]), f2bf(q[i * 4 + 1]),
                                  f2bf(q[i * 4 + 2]), f2bf(q[i * 4 + 3]));
        *(ushort4*)(A16 + i * 4) = ov;
    }
}

// Kernel 3: cpart[ks][b][m][n] = sum_{k in split} A[m][k] * seqT[n][k]  (bf16 MFMA)
__global__ __launch_bounds__(256) void k3_gemm(float* __restrict__ ws) {
    int m0 = blockIdx.x * 64, n0 = blockIdx.y * 64;
    int ks = blockIdx.z & (KS - 1), b = blockIdx.z >> 3;
    const unsigned short* A = (const unsigned short*)(ws + A16_OFF) + (size_t)b * MM * LL;
    const unsigned short* Bm = (const unsigned short*)(ws + SQT_OFF) + (size_t)b * DD * LL;
    __shared__ __align__(16) short As[64][40];
    __shared__ __align__(16) short Bs[64][40];
    int t = threadIdx.x;
    int row = t >> 2, seg = t & 3;
    int w = t >> 6, lane = t & 63;
    int wr = w >> 1, wc = w & 1;
    int fr = lane & 15, kb = lane >> 4;
    f32x4 acc[2][2] = {};
    int k0c = ks * KCH;
    for (int st = 0; st < KCH / 32; ++st) {
        int kk = k0c + st * 32;
        *(uint4*)&As[row][seg * 8] = *(const uint4*)(A + (size_t)(m0 + row) * LL + kk + seg * 8);
        *(uint4*)&Bs[row][seg * 8] = *(const uint4*)(Bm + (size_t)(n0 + row) * LL + kk + seg * 8);
        __syncthreads();
        bf16x8 af[2], bfr[2];
        #pragma unroll
        for (int i = 0; i < 2; ++i) af[i] = *(bf16x8*)&As[wr * 32 + i * 16 + fr][kb * 8];
        #pragma unroll
        for (int j = 0; j < 2; ++j) bfr[j] = *(bf16x8*)&Bs[wc * 32 + j * 16 + fr][kb * 8];
        #pragma unroll
        for (int i = 0; i < 2; ++i)
            #pragma unroll
            for (int j = 0; j < 2; ++j)
                acc[i][j] = __builtin_amdgcn_mfma_f32_16x16x32_bf16(af[i], bfr[j], acc[i][j], 0, 0, 0);
        __syncthreads();
    }
    float* cp = ws + CPART_OFF + (size_t)((ks * BB + b) * MM) * DD;
    #pragma unroll
    for (int i = 0; i < 2; ++i)
        #pragma unroll
        for (int j = 0; j < 2; ++j)
            #pragma unroll
            for (int r = 0; r < 4; ++r) {
                int gm = m0 + wr * 32 + i * 16 + kb * 4 + r;
                int gn = n0 + wc * 32 + j * 16 + fr;
                cp[(size_t)gm * DD + gn] = acc[i][j][r];
            }
}

// Kernel 4: qsum + emb in REGISTERS (4 pairs x 9 float4 per lane) + scoring
__global__ __launch_bounds__(256, 1) void k4_score(const float* __restrict__ rel,
                                                   const float* __restrict__ nota,
                                                   const float* __restrict__ ws,
                                                   float* __restrict__ out) {
    int pt = blockIdx.x, b = blockIdx.y;
    int tid = threadIdx.x, w = tid >> 6, lane = tid & 63;
    __shared__ float red_s[4][PT4];
    __shared__ float qs_s[PT4];
    __shared__ float nota_s[PT4][NN];
    // phase 0: qsum per pair (from bf16 q rows)
    {
        const unsigned short* A16 =
            (const unsigned short*)(ws + A16_OFF) + (size_t)(b * MM + pt * PT4) * LL;
        #pragma unroll
        for (int j = 0; j < PT4; ++j) {
            ushort4 u0 = *(const ushort4*)(A16 + (size_t)j * LL + tid * 8);
            ushort4 u1 = *(const ushort4*)(A16 + (size_t)j * LL + tid * 8 + 4);
            float v = bf2f(u0.x) + bf2f(u0.y) + bf2f(u0.z) + bf2f(u0.w)
                    + bf2f(u1.x) + bf2f(u1.y) + bf2f(u1.z) + bf2f(u1.w);
            #pragma unroll
            for (int off = 32; off > 0; off >>= 1) v += __shfl_xor(v, off, 64);
            if (lane == 0) red_s[w][j] = v;
        }
        __syncthreads();
        if (tid < PT4)
            qs_s[tid] = 1.0f / (red_s[0][tid] + red_s[1][tid] + red_s[2][tid] + red_s[3][tid]);
        __syncthreads();
    }
    // phase 1: per-lane emb fragments for ALL 4 pairs: er[j][i4] = emb[j][(i4*64+lane)*4 ..]
    float4 er[PT4][9];
    #pragma unroll
    for (int j = 0; j < PT4; ++j) {
        int p = pt * PT4 + j;
        int s, o;
        pair_so(p, s, o);
        const float4* es = (const float4*)(ws + ENT_EMB_OFF + (size_t)(b * EE + s) * DD);
        const float4* eo = (const float4*)(ws + ENT_EMB_OFF + (size_t)(b * EE + o) * DD);
        float qs = qs_s[j];
        #pragma unroll
        for (int i4 = 0; i4 < 3; ++i4) er[j][i4] = es[i4 * 64 + lane];
        #pragma unroll
        for (int i4 = 0; i4 < 3; ++i4) er[j][3 + i4] = eo[i4 * 64 + lane];
        #pragma unroll
        for (int i4 = 0; i4 < 3; ++i4) {
            float4 sum = make_float4(0.f, 0.f, 0.f, 0.f);
            #pragma unroll
            for (int ls = 0; ls < KS; ++ls) {
                const float4* cp = (const float4*)(ws + CPART_OFF +
                                   (size_t)((ls * BB + b) * MM + p) * DD);
                float4 v = cp[i4 * 64 + lane];
                sum.x += v.x; sum.y += v.y; sum.z += v.z; sum.w += v.w;
            }
            er[j][6 + i4] = make_float4(sum.x * qs, sum.y * qs, sum.z * qs, sum.w * qs);
        }
    }
    // phase 2: each wave scores rows w, w+4, ... (code read once per block per row)
    for (int rowi = w; rowi < RR + NN; rowi += 4) {
        const float4* code = (rowi < RR)
            ? (const float4*)(rel + (size_t)rowi * 3 * DD)
            : (const float4*)(nota + (size_t)(rowi - RR) * 3 * DD);
        float acc[PT4] = {0.f, 0.f, 0.f, 0.f};
        #pragma unroll
        for (int i4 = 0; i4 < 9; ++i4) {
            float4 cv = code[i4 * 64 + lane];
            #pragma unroll
            for (int j = 0; j < PT4; ++j) {
                acc[j] += cv.x * er[j][i4].x + cv.y * er[j][i4].y
                        + cv.z * er[j][i4].z + cv.w * er[j][i4].w;
            }
        }
        #pragma unroll
        for (int j = 0; j < PT4; ++j) {
            float v = acc[j];
            #pragma unroll
            for (int off = 32; off > 0; off >>= 1) v += __shfl_xor(v, off, 64);
            if (lane == 0) {
                int p = pt * PT4 + j;
                if (rowi < RR) out[(size_t)(b * PP + p) * (RR + 1) + 1 + rowi] = v;
                else nota_s[j][rowi - RR] = v;
            }
        }
    }
    __syncthreads();
    if (tid < PT4) {
        float m = -INFINITY;
        #pragma unroll
        for (int n = 0; n < NN; ++n) m = fmaxf(m, nota_s[tid][n]);
        out[(size_t)(b * PP + pt * PT4 + tid) * (RR + 1)] = m;
    }
}

extern "C" void kernel_launch(void* const* d_in, const int* in_sizes, int n_in,
                              void* d_out, int out_size, void* d_ws, size_t ws_size,
                              hipStream_t stream) {
    const float* seq   = (const float*)d_in[0];
    const float* att   = (const float*)d_in[1];
    const float* rel   = (const float*)d_in[2];
    const float* nota  = (const float*)d_in[3];
    const int*   spans = (const int*)d_in[4];
    float* ws  = (float*)d_ws;
    float* out = (float*)d_out;

    k1_prep<<<3072 + EE * BB, 256, 0, stream>>>(seq, spans, ws);
    k2_q<<<dim3(LL / 32, BB), 256, 0, stream>>>(att, spans, ws);
    k3_gemm<<<dim3(MM / 64, DD / 64, KS * BB), 256, 0, stream>>>(ws);
    k4_score<<<dim3(NPT4, BB), 256, 0, stream>>>(rel, nota, ws, out);
}